// Round 19
// baseline (147.349 us; speedup 1.0000x reference)
//
#include <hip/hip_runtime.h>
#include <hip/hip_bf16.h>
#include <stdint.h>

typedef __bf16 bf16_t;
typedef bf16_t bf16x4 __attribute__((ext_vector_type(4)));
typedef bf16_t bf16x8 __attribute__((ext_vector_type(8)));
typedef float  f32x4  __attribute__((ext_vector_type(4)));

#define B_   4
#define T_   1024
#define C_   1024
#define H_   16

__device__ __forceinline__ f32x4 mfma_bf16(bf16x8 a, bf16x8 b, f32x4 c) {
  return __builtin_amdgcn_mfma_f32_16x16x32_bf16(a, b, c, 0, 0, 0);
}

__device__ __forceinline__ void async16(const bf16_t* g, bf16_t* l) {
  __builtin_amdgcn_global_load_lds(
      (__attribute__((address_space(1))) void*)(uintptr_t)g,
      (__attribute__((address_space(3))) void*)l, 16, 0, 0);
}

// ---------------------------------------------------------------- prep_all
// One launch, block-range dispatch (r16-verified):
//   [0,7168)      : f32->bf16 convert of x + c_attn_w
//   [7168,11264)  : 4-slab weight transpose (slab3 = (ln_g ⊙ out_w)^T)
//   [11264,11345) : qkv effective bias / svec / c2v / zero ssum+ssq
__global__ __launch_bounds__(256) void prep_all(
    const float* __restrict__ x, bf16_t* __restrict__ xb,
    const float* __restrict__ caw, bf16_t* __restrict__ cawb,
    const float* __restrict__ qw, const float* __restrict__ kw,
    const float* __restrict__ vw, const float* __restrict__ ow,
    const float* __restrict__ lng, bf16_t* __restrict__ WsT4,
    const float* __restrict__ cb,
    const float* __restrict__ qb, const float* __restrict__ kb,
    const float* __restrict__ vb,
    const float* __restrict__ lnb, const float* __restrict__ outb,
    float* __restrict__ out_qkv, float* __restrict__ svec,
    float* __restrict__ c2v, float* __restrict__ ssum, float* __restrict__ ssq)
{
  __shared__ bf16_t tile[32][33];
  __shared__ float part[4][64];
  const int bid = blockIdx.x;
  const int tid = threadIdx.x;

  if (bid < 7168) {                       // ---- convert
    const int i = bid * 256 + tid;
    const float* src; bf16_t* dst; int idx;
    if (i < 1048576) { src = x; dst = xb; idx = i; }
    else { src = caw; dst = cawb; idx = i - 1048576; }
    const float4 v = *(const float4*)(src + (size_t)idx * 4);
    bf16x4 o;
    o[0] = (bf16_t)v.x; o[1] = (bf16_t)v.y; o[2] = (bf16_t)v.z; o[3] = (bf16_t)v.w;
    *(bf16x4*)(dst + (size_t)idx * 4) = o;
    return;
  }
  if (bid < 11264) {                      // ---- transpose 4 slabs
    const int b2 = bid - 7168;
    const int z = b2 >> 10, rem = b2 & 1023;
    const int bx = rem & 31, by = rem >> 5;
    const float* in = (z == 0) ? qw : (z == 1) ? kw : (z == 2) ? vw : ow;
    bf16_t* o = WsT4 + ((size_t)z << 20);
    const int n0 = bx * 32, k0 = by * 32;
    const int xl = tid & 31, y4 = (tid >> 5) * 4;
#pragma unroll
    for (int i = 0; i < 4; ++i) {
      float v = in[(size_t)(k0 + y4 + i) * 1024 + n0 + xl];
      if (z == 3) v *= lng[k0 + y4 + i];
      tile[y4 + i][xl] = (bf16_t)v;
    }
    __syncthreads();
#pragma unroll
    for (int i = 0; i < 4; ++i)
      o[(size_t)(n0 + y4 + i) * 1024 + k0 + xl] = tile[xl][y4 + i];
    return;
  }
  const int pbid = bid - 11264;           // ---- prep vectors
  if (pbid >= 80) {
    const float4 z4 = {0.f, 0.f, 0.f, 0.f};
#pragma unroll
    for (int k = 0; k < 4; ++k) {
      ((float4*)ssum)[tid * 4 + k] = z4;
      ((float4*)ssq)[tid * 4 + k] = z4;
    }
    return;
  }
  const int jl = tid & 63, cq = tid >> 6;
  const int c0 = cq * 256;
  if (pbid < 48) {
    const int j = pbid * 64 + jl;
    const int s = j >> 10, jj = j & 1023;
    const float* w  = (s == 0) ? qw : (s == 1) ? kw : vw;
    const float* sb = (s == 0) ? qb : (s == 1) ? kb : vb;
    float acc = 0.f;
#pragma unroll 8
    for (int c = c0; c < c0 + 256; ++c)
      acc += cb[s * 1024 + c] * w[(size_t)c * 1024 + jj];
    part[cq][jl] = acc;
    __syncthreads();
    if (cq == 0)
      out_qkv[j] = part[0][jl] + part[1][jl] + part[2][jl] + part[3][jl] + sb[jj];
  } else {
    const int jj = (pbid - 48) * 64 + jl;  // [0,2048)
    const int col = jj & 1023;
    const float* coef = (jj < 1024) ? lng : lnb;
    float acc = 0.f;
#pragma unroll 8
    for (int c = c0; c < c0 + 256; ++c)
      acc += coef[c] * ow[(size_t)c * 1024 + col];
    part[cq][jl] = acc;
    __syncthreads();
    if (cq == 0) {
      const float tot = part[0][jl] + part[1][jl] + part[2][jl] + part[3][jl];
      if (jj < 1024) svec[col] = tot;
      else           c2v[col] = tot + outb[col];
    }
  }
}

// ---------------------------------------------------------------- v_frag
__global__ __launch_bounds__(256) void transpose_v(
    const bf16_t* __restrict__ qkvb, bf16_t* __restrict__ vfrag)
{
  __shared__ bf16_t tile[64][66];   // tile[f][key]
  const int bid = blockIdx.x;
  const int kb = bid & 15, bh = bid >> 4;
  const int b = bh >> 4, h = bh & 15;
  const int t = threadIdx.x;
  {
    const int key = t & 63, fc = (t >> 6) * 16;
    const bf16_t* src =
        qkvb + (size_t)(b * 1024 + kb * 64 + key) * 3072 + 2048 + h * 64 + fc;
    bf16x8 v0 = *(const bf16x8*)src;
    bf16x8 v1 = *(const bf16x8*)(src + 8);
#pragma unroll
    for (int j = 0; j < 8; ++j) {
      tile[fc + j][key]     = v0[j];
      tile[fc + 8 + j][key] = v1[j];
    }
  }
  __syncthreads();
#pragma unroll
  for (int ww = 0; ww < 2; ++ww) {
    const int g = t * 2 + ww;
    const int chunk = g >> 6;
    const int lane2 = g & 63;
    const int lr2 = lane2 & 15, lg2 = lane2 >> 4;
    const int kk = chunk >> 2, nf = chunk & 3;
    const int f = nf * 16 + lr2;
    const int key0 = kk * 32 + lg2 * 8;
    bf16x8 val;
#pragma unroll
    for (int j = 0; j < 8; ++j) val[j] = tile[f][key0 + j];
    *(bf16x8*)&vfrag[(((size_t)bh * 16 + kb) * 8 + chunk) * 512 + lane2 * 8] = val;
  }
}

// ---------------------------------------------------------------- GEMM (TMxTN)
// T2 swizzle (conflicts=0) + counted-vmcnt 3-buffer pipeline (r13-verified),
// tile = (32*TM) x (32*TN), 4 waves (2x2). LPS = loads/thread/stage.
template <typename OT, int TM, int TN>
__global__ __launch_bounds__(256) void gemm_bt_bias(
    const bf16_t* __restrict__ A, int lda,
    const bf16_t* __restrict__ Bt, int ldb,
    const float* __restrict__ bias,
    OT* __restrict__ C, int ldc,
    int K, int nTilesN, int blocksPerMat,
    int strideA, int strideB, int strideC, int xcdSwz)
{
  constexpr int TILEM = 32 * TM, TILEN = 32 * TN;
  constexpr int LPS = TM / 2 + TN / 2;
  __shared__ __align__(16) bf16_t As[3][TILEM * 32];
  __shared__ __align__(16) bf16_t Bs[3][TILEN * 32];
  int raw = blockIdx.x;
  if (xcdSwz) {
    const int cpx = gridDim.x >> 3;
    raw = (raw & 7) * cpx + (raw >> 3);
  }
  const int s   = raw / blocksPerMat;
  const int bid = raw % blocksPerMat;
  A  += (size_t)s * strideA;
  Bt += (size_t)s * strideB;
  C  += (size_t)s * strideC;
  const int mt = bid / nTilesN, nt = bid % nTilesN;
  const int m0 = mt * TILEM, n0 = nt * TILEN;
  const int tid = threadIdx.x;
  const int lane = tid & 63;
  const int lr = lane & 15, lg = lane >> 4;
  const int wid = tid >> 6;
  const int wr = wid >> 1, wc = wid & 1;
  const int sLg = lg ^ ((lr >> 1) & 3);

  f32x4 acc[TM][TN];
#pragma unroll
  for (int m = 0; m < TM; ++m)
#pragma unroll
    for (int n = 0; n < TN; ++n) acc[m][n] = (f32x4){0.f, 0.f, 0.f, 0.f};

  const int nk = K >> 5;

  auto stage = [&](int buf, int t) {
    const int k0 = t << 5;
#pragma unroll
    for (int p = 0; p < TM / 2; ++p) {
      const int c = p * 256 + tid;
      const int row = c >> 2;
      const int col = (((c & 3) ^ ((c >> 3) & 3)) << 3);
      async16(A + (size_t)(m0 + row) * lda + k0 + col, &As[buf][c * 8]);
    }
#pragma unroll
    for (int p = 0; p < TN / 2; ++p) {
      const int c = p * 256 + tid;
      const int row = c >> 2;
      const int col = (((c & 3) ^ ((c >> 3) & 3)) << 3);
      async16(Bt + (size_t)(n0 + row) * ldb + k0 + col, &Bs[buf][c * 8]);
    }
  };

  stage(0, 0);
  stage(1, 1);
  if constexpr (LPS == 4)
    asm volatile("s_waitcnt vmcnt(4)" ::: "memory");
  else if constexpr (LPS == 3)
    asm volatile("s_waitcnt vmcnt(3)" ::: "memory");
  else
    asm volatile("s_waitcnt vmcnt(2)" ::: "memory");
  __builtin_amdgcn_sched_barrier(0);
  __builtin_amdgcn_s_barrier();
  __builtin_amdgcn_sched_barrier(0);

  for (int t = 0; t < nk; ++t) {
    const int buf = t % 3;
    if (t + 2 < nk) stage((t + 2) % 3, t + 2);

    bf16x8 af[TM], bfr[TN];
#pragma unroll
    for (int m = 0; m < TM; ++m)
      af[m] = *(const bf16x8*)
          &As[buf][(wr * TM * 16 + m * 16 + lr) * 32 + sLg * 8];
#pragma unroll
    for (int n = 0; n < TN; ++n)
      bfr[n] = *(const bf16x8*)
          &Bs[buf][(wc * TN * 16 + n * 16 + lr) * 32 + sLg * 8];

    if (t + 2 < nk) {
      if constexpr (LPS == 4)
        asm volatile("s_waitcnt lgkmcnt(0) vmcnt(4)" ::: "memory");
      else if constexpr (LPS == 3)
        asm volatile("s_waitcnt lgkmcnt(0) vmcnt(3)" ::: "memory");
      else
        asm volatile("s_waitcnt lgkmcnt(0) vmcnt(2)" ::: "memory");
    } else {
      asm volatile("s_waitcnt lgkmcnt(0) vmcnt(0)" ::: "memory");
    }
    __builtin_amdgcn_sched_barrier(0);
    __builtin_amdgcn_s_barrier();
    __builtin_amdgcn_sched_barrier(0);

    __builtin_amdgcn_s_setprio(1);
#pragma unroll
    for (int m = 0; m < TM; ++m)
#pragma unroll
      for (int n = 0; n < TN; ++n)
        acc[m][n] = mfma_bf16(af[m], bfr[n], acc[m][n]);
    __builtin_amdgcn_s_setprio(0);
  }

#pragma unroll
  for (int n = 0; n < TN; ++n) {
    const int col = n0 + wc * TN * 16 + n * 16 + lr;
    const float bv = bias ? bias[col] : 0.0f;
#pragma unroll
    for (int m = 0; m < TM; ++m) {
      const int row = m0 + wr * TM * 16 + m * 16 + lg * 4;
#pragma unroll
      for (int r = 0; r < 4; ++r)
        C[(size_t)(row + r) * ldc + col] = (OT)(acc[m][n][r] + bv);
    }
  }
}

// ---------------------------------------------------------------- GEMM + LN
// Final projection with LayerNorm folded in (r15-verified math), 64x64 tiles
// (r17-verified: ~4/CU occupancy).
__global__ __launch_bounds__(256) void gemm_ln(
    const bf16_t* __restrict__ A, int lda,
    const bf16_t* __restrict__ Bt, int ldb,
    const float* __restrict__ svec, const float* __restrict__ c2v,
    const float* __restrict__ ssum, const float* __restrict__ ssq,
    float* __restrict__ C, int ldc, int K, int nTilesN)
{
  __shared__ __align__(16) bf16_t As[3][64 * 32];
  __shared__ __align__(16) bf16_t Bs[3][64 * 32];
  int raw = blockIdx.x;
  {
    const int cpx = gridDim.x >> 3;
    raw = (raw & 7) * cpx + (raw >> 3);
  }
  const int mt = raw / nTilesN, nt = raw % nTilesN;
  const int m0 = mt * 64, n0 = nt * 64;
  const int tid = threadIdx.x;
  const int lane = tid & 63;
  const int lr = lane & 15, lg = lane >> 4;
  const int wid = tid >> 6;
  const int wr = wid >> 1, wc = wid & 1;
  const int sLg = lg ^ ((lr >> 1) & 3);

  f32x4 acc[2][2];
#pragma unroll
  for (int m = 0; m < 2; ++m)
#pragma unroll
    for (int n = 0; n < 2; ++n) acc[m][n] = (f32x4){0.f, 0.f, 0.f, 0.f};

  const int nk = K >> 5;

  auto stage = [&](int buf, int t) {
    const int k0 = t << 5;
    const int c = tid;
    const int row = c >> 2;
    const int col = (((c & 3) ^ ((c >> 3) & 3)) << 3);
    async16(A + (size_t)(m0 + row) * lda + k0 + col, &As[buf][c * 8]);
    async16(Bt + (size_t)(n0 + row) * ldb + k0 + col, &Bs[buf][c * 8]);
  };

  stage(0, 0);
  stage(1, 1);
  asm volatile("s_waitcnt vmcnt(2)" ::: "memory");
  __builtin_amdgcn_sched_barrier(0);
  __builtin_amdgcn_s_barrier();
  __builtin_amdgcn_sched_barrier(0);

  for (int t = 0; t < nk; ++t) {
    const int buf = t % 3;
    if (t + 2 < nk) stage((t + 2) % 3, t + 2);

    bf16x8 af[2], bfr[2];
#pragma unroll
    for (int m = 0; m < 2; ++m)
      af[m] = *(const bf16x8*)&As[buf][(wr * 32 + m * 16 + lr) * 32 + sLg * 8];
#pragma unroll
    for (int n = 0; n < 2; ++n)
      bfr[n] = *(const bf16x8*)&Bs[buf][(wc * 32 + n * 16 + lr) * 32 + sLg * 8];

    if (t + 2 < nk)
      asm volatile("s_waitcnt lgkmcnt(0) vmcnt(2)" ::: "memory");
    else
      asm volatile("s_waitcnt lgkmcnt(0) vmcnt(0)" ::: "memory");
    __builtin_amdgcn_sched_barrier(0);
    __builtin_amdgcn_s_barrier();
    __builtin_amdgcn_sched_barrier(0);

    __builtin_amdgcn_s_setprio(1);
#pragma unroll
    for (int m = 0; m < 2; ++m)
#pragma unroll
      for (int n = 0; n < 2; ++n)
        acc[m][n] = mfma_bf16(af[m], bfr[n], acc[m][n]);
    __builtin_amdgcn_s_setprio(0);
  }

#pragma unroll
  for (int n = 0; n < 2; ++n) {
    const int col = n0 + wc * 32 + n * 16 + lr;
    const float sj = svec[col];
    const float c2 = c2v[col];
#pragma unroll
    for (int m = 0; m < 2; ++m) {
      const int row = m0 + wr * 32 + m * 16 + lg * 4;
      const float* s1 = &ssum[row];
      const float* s2 = &ssq[row];
#pragma unroll
      for (int r = 0; r < 4; ++r) {
        const float mu  = s1[r] * (1.0f / 1024.0f);
        const float var = s2[r] * (1.0f / 1024.0f) - mu * mu;
        const float al  = rsqrtf(var + 1e-5f);
        C[(size_t)(row + r) * ldc + col] = al * acc[m][n][r] - al * mu * sj + c2;
      }
    }
  }
}

// ---------------------------------------------------------------- attention
// LDS-staged flash attention (r9-verified math) — single-band blocks with
// longest-first dispatch for backfill: 1024 blocks, block = one 64-row q-band
// (band = 15 - (idx&15) so 16-tile bands launch first; no lockstep pairing).
// 3 blocks/CU resident by LDS (41.2 KB); XCD clustering preserved.
__global__ __launch_bounds__(256) void attn_kernel(
    const bf16_t* __restrict__ qkv, const bf16_t* __restrict__ vfrag,
    bf16_t* __restrict__ o, float* __restrict__ ssum, float* __restrict__ ssq)
{
  __shared__ __align__(16) bf16_t Ks[2][8][512];
  __shared__ __align__(16) bf16_t Vs[2][8][512];
  __shared__ __align__(16) bf16_t Ps[4][16][72];
  const int LD = 3072;
  const bf16_t* q = qkv;
  const bf16_t* k = qkv + 1024;

  const int raw = blockIdx.x;
  const int xcd = raw & 7, idx = raw >> 3;
  const int bh   = (idx >> 4) * 8 + xcd;   // all 16 bands of a bh on one XCD
  const int band = 15 - (idx & 15);        // longest bands dispatch first
  const int b = bh >> 4, h = bh & 15;

  const int tid = threadIdx.x;
  const int lane = tid & 63;
  const int lr = lane & 15, lg = lane >> 4;
  const int w = tid >> 6;

  const bf16_t* kbase = k + (size_t)(b * T_) * LD + h * 64;
  const bf16_t* vfbase = vfrag + (size_t)bh * 16 * 8 * 512;

  auto stage = [&](int bf, int it) {
    const int kv0 = it << 6;
#pragma unroll
    for (int cc = 0; cc < 4; ++cc) {
      const int c = w * 4 + cc;
      if (c < 8) {
        const int kg = c >> 1, kk = c & 1;
        async16(kbase + (size_t)(kv0 + kg * 16 + lr) * LD + kk * 32 + lg * 8,
                &Ks[bf][c][lane * 8]);
      } else {
        const int cv = c - 8;
        async16(vfbase + ((size_t)it * 8 + cv) * 512 + lane * 8,
                &Vs[bf][cv][lane * 8]);
      }
    }
  };

  const int myq = band * 64 + w * 16 + lr;
  const int nIter = band + 1;

  bf16x8 qf[2];
  {
    const size_t qr = (size_t)(b * T_ + myq) * LD + h * 64;
    qf[0] = *(const bf16x8*)&q[qr + lg * 8];
    qf[1] = *(const bf16x8*)&q[qr + 32 + lg * 8];
  }

  float mi = -3.0e38f, li = 0.0f;
  f32x4 acc[4];
#pragma unroll
  for (int nf = 0; nf < 4; ++nf) acc[nf] = (f32x4){0.f, 0.f, 0.f, 0.f};

  stage(0, 0);
  __syncthreads();

  for (int it = 0; it < nIter; ++it) {
    const int bf = it & 1;
    if (it + 1 < nIter) stage(bf ^ 1, it + 1);
    const int kv0 = it << 6;

    f32x4 sfr[4];
    __builtin_amdgcn_s_setprio(1);
#pragma unroll
    for (int kg = 0; kg < 4; ++kg) {
      bf16x8 kf0 = *(const bf16x8*)&Ks[bf][kg * 2 + 0][lane * 8];
      bf16x8 kf1 = *(const bf16x8*)&Ks[bf][kg * 2 + 1][lane * 8];
      f32x4 z = (f32x4){0.f, 0.f, 0.f, 0.f};
      z = mfma_bf16(kf0, qf[0], z);
      z = mfma_bf16(kf1, qf[1], z);
      sfr[kg] = z;
    }
    __builtin_amdgcn_s_setprio(0);

    float sv[4][4];
    float pm[4];
#pragma unroll
    for (int kg = 0; kg < 4; ++kg) {
      const int keyb = kv0 + kg * 16 + lg * 4;
      pm[kg] = -3.0e38f;
#pragma unroll
      for (int r = 0; r < 4; ++r) {
        float xx = sfr[kg][r] * 0.015625f;
        if (keyb + r > myq) xx = -3.0e38f;
        sv[kg][r] = xx;
        pm[kg] = fmaxf(pm[kg], xx);
      }
    }
    float pmax = fmaxf(fmaxf(pm[0], pm[1]), fmaxf(pm[2], pm[3]));
    pmax = fmaxf(pmax, __shfl_xor(pmax, 16));
    pmax = fmaxf(pmax, __shfl_xor(pmax, 32));
    const float mnew = fmaxf(mi, pmax);
    const float fr = __expf(mi - mnew);
    mi = mnew;
    float ps[4];
#pragma unroll
    for (int kg = 0; kg < 4; ++kg) {
      float p0 = __expf(sv[kg][0] - mi);
      float p1 = __expf(sv[kg][1] - mi);
      float p2 = __expf(sv[kg][2] - mi);
      float p3 = __expf(sv[kg][3] - mi);
      sv[kg][0] = p0; sv[kg][1] = p1; sv[kg][2] = p2; sv[kg][3] = p3;
      ps[kg] = (p0 + p1) + (p2 + p3);
    }
    float psum = (ps[0] + ps[1]) + (ps[2] + ps[3]);
    psum += __shfl_xor(psum, 16);
    psum += __shfl_xor(psum, 32);
    li = li * fr + psum;
#pragma unroll
    for (int nf = 0; nf < 4; ++nf)
#pragma unroll
      for (int r = 0; r < 4; ++r) acc[nf][r] *= fr;

#pragma unroll
    for (int kg = 0; kg < 4; ++kg) {
      bf16x4 p4;
#pragma unroll
      for (int r = 0; r < 4; ++r) p4[r] = (bf16_t)sv[kg][r];
      *(bf16x4*)&Ps[w][lr][kg * 16 + lg * 4] = p4;
    }

    __builtin_amdgcn_s_setprio(1);
#pragma unroll
    for (int kk = 0; kk < 2; ++kk) {
      bf16x8 pf = *(const bf16x8*)&Ps[w][lr][kk * 32 + lg * 8];
#pragma unroll
      for (int nf = 0; nf < 4; ++nf) {
        bf16x8 vf = *(const bf16x8*)&Vs[bf][kk * 4 + nf][lane * 8];
        acc[nf] = mfma_bf16(vf, pf, acc[nf]);
      }
    }
    __builtin_amdgcn_s_setprio(0);

    __syncthreads();
  }

  const float inv = 1.0f / li;
  float st1 = 0.f, st2 = 0.f;
#pragma unroll
  for (int nf = 0; nf < 4; ++nf) {
    bf16x4 o4;
#pragma unroll
    for (int r = 0; r < 4; ++r) {
      const float ov = acc[nf][r] * inv;
      o4[r] = (bf16_t)ov;
      st1 += ov;
      st2 += ov * ov;
    }
    *(bf16x4*)&o[(size_t)(b * T_ + myq) * C_ + h * 64 + nf * 16 + lg * 4] = o4;
  }
  st1 += __shfl_xor(st1, 16); st1 += __shfl_xor(st1, 32);
  st2 += __shfl_xor(st2, 16); st2 += __shfl_xor(st2, 32);
  if (lg == 0) {
    atomicAdd(&ssum[b * T_ + myq], st1);
    atomicAdd(&ssq[b * T_ + myq], st2);
  }
}

// ---------------------------------------------------------------- launch
extern "C" void kernel_launch(void* const* d_in, const int* in_sizes, int n_in,
                              void* d_out, int out_size, void* d_ws, size_t ws_size,
                              hipStream_t stream)
{
  const float* x        = (const float*)d_in[0];
  const float* c_attn_w = (const float*)d_in[1];
  const float* c_attn_b = (const float*)d_in[2];
  const float* q_w      = (const float*)d_in[3];
  const float* q_b      = (const float*)d_in[4];
  const float* k_w      = (const float*)d_in[5];
  const float* k_b      = (const float*)d_in[6];
  const float* v_w      = (const float*)d_in[7];
  const float* v_b      = (const float*)d_in[8];
  const float* ln_g     = (const float*)d_in[9];
  const float* ln_b     = (const float*)d_in[10];
  const float* out_w    = (const float*)d_in[11];
  const float* out_b    = (const float*)d_in[12];

  char* ws = (char*)d_ws;
  bf16_t* qkvb      = (bf16_t*)(ws + 0);          // [4096][3072]
  bf16_t* xb        = (bf16_t*)(ws + 25165824);   // [4096][1024] dead after qkv
  bf16_t* ob        = (bf16_t*)(ws + 25165824);   // attn output (overlays xb)
  bf16_t* WsT4      = (bf16_t*)(ws + 33554432);   // 4 slabs of 1M bf16
  bf16_t* c_attn_wb = (bf16_t*)(ws + 41943040);   // [1024][3072]
  bf16_t* Wt_eff    = (bf16_t*)(ws + 48234496);   // [3072][1024]
  float*  bias_eff  = (float*)(ws + 54525952);    // [3072]
  bf16_t* vfrag     = (bf16_t*)(ws + 54538240);   // 8 MB fragment-linear V
  float*  ssum      = (float*)(ws + 62926848);    // [4096]
  float*  ssq       = (float*)(ws + 62943232);    // [4096]
  float*  svec      = (float*)(ws + 62959616);    // [1024]
  float*  c2v       = (float*)(ws + 62963712);    // [1024]

  prep_all<<<dim3(11345), 256, 0, stream>>>(
      x, xb, c_attn_w, c_attn_wb,
      q_w, k_w, v_w, out_w, ln_g, WsT4,
      c_attn_b, q_b, k_b, v_b, ln_b, out_b,
      bias_eff, svec, c2v, ssum, ssq);

  // fused weights: 64x64 tiles, 768 blocks (r16-verified)
  gemm_bt_bias<bf16_t, 2, 2><<<dim3(768), 256, 0, stream>>>(
      WsT4, 1024, c_attn_wb, 3072, nullptr, Wt_eff, 1024,
      1024, 16, 256, 1 << 20, 1024, 1 << 20, 1);

  // qkvb = xb @ Wt_eff^T + bias_eff (128x128, 768 blocks — r16-verified best)
  gemm_bt_bias<bf16_t, 4, 4><<<dim3(768), 256, 0, stream>>>(
      xb, 1024, Wt_eff, 1024, bias_eff, qkvb, 3072, 1024, 24, 768, 0, 0, 0, 1);

  transpose_v<<<dim3(1024), 256, 0, stream>>>(qkvb, vfrag);

  // attention: 1024 single-band blocks, longest-first (backfill scheduling)
  attn_kernel<<<dim3(1024), 256, 0, stream>>>(qkvb, vfrag, ob, ssum, ssq);

  // final GEMM+LN: 64x64 tiles, 1024 blocks (r17-verified)
  gemm_ln<<<dim3(1024), 256, 0, stream>>>(
      ob, 1024, WsT4 + (size_t)3 * (1 << 20), 1024,
      svec, c2v, ssum, ssq, (float*)d_out, 1024, 1024, 16);
}

// Round 20
// 138.592 us; speedup vs baseline: 1.0632x; 1.0632x over previous
//
#include <hip/hip_runtime.h>
#include <hip/hip_bf16.h>
#include <stdint.h>

typedef __bf16 bf16_t;
typedef bf16_t bf16x4 __attribute__((ext_vector_type(4)));
typedef bf16_t bf16x8 __attribute__((ext_vector_type(8)));
typedef float  f32x4  __attribute__((ext_vector_type(4)));

#define B_   4
#define T_   1024
#define C_   1024
#define H_   16

__device__ __forceinline__ f32x4 mfma_bf16(bf16x8 a, bf16x8 b, f32x4 c) {
  return __builtin_amdgcn_mfma_f32_16x16x32_bf16(a, b, c, 0, 0, 0);
}

__device__ __forceinline__ void async16(const bf16_t* g, bf16_t* l) {
  __builtin_amdgcn_global_load_lds(
      (__attribute__((address_space(1))) void*)(uintptr_t)g,
      (__attribute__((address_space(3))) void*)l, 16, 0, 0);
}

// ---------------------------------------------------------------- prep_all
// One launch, block-range dispatch (r16-verified):
//   [0,7168)      : f32->bf16 convert of x + c_attn_w
//   [7168,11264)  : 4-slab weight transpose (slab3 = (ln_g ⊙ out_w)^T)
//   [11264,11345) : qkv effective bias / svec / c2v / zero ssum+ssq
__global__ __launch_bounds__(256) void prep_all(
    const float* __restrict__ x, bf16_t* __restrict__ xb,
    const float* __restrict__ caw, bf16_t* __restrict__ cawb,
    const float* __restrict__ qw, const float* __restrict__ kw,
    const float* __restrict__ vw, const float* __restrict__ ow,
    const float* __restrict__ lng, bf16_t* __restrict__ WsT4,
    const float* __restrict__ cb,
    const float* __restrict__ qb, const float* __restrict__ kb,
    const float* __restrict__ vb,
    const float* __restrict__ lnb, const float* __restrict__ outb,
    float* __restrict__ out_qkv, float* __restrict__ svec,
    float* __restrict__ c2v, float* __restrict__ ssum, float* __restrict__ ssq)
{
  __shared__ bf16_t tile[32][33];
  __shared__ float part[4][64];
  const int bid = blockIdx.x;
  const int tid = threadIdx.x;

  if (bid < 7168) {                       // ---- convert
    const int i = bid * 256 + tid;
    const float* src; bf16_t* dst; int idx;
    if (i < 1048576) { src = x; dst = xb; idx = i; }
    else { src = caw; dst = cawb; idx = i - 1048576; }
    const float4 v = *(const float4*)(src + (size_t)idx * 4);
    bf16x4 o;
    o[0] = (bf16_t)v.x; o[1] = (bf16_t)v.y; o[2] = (bf16_t)v.z; o[3] = (bf16_t)v.w;
    *(bf16x4*)(dst + (size_t)idx * 4) = o;
    return;
  }
  if (bid < 11264) {                      // ---- transpose 4 slabs
    const int b2 = bid - 7168;
    const int z = b2 >> 10, rem = b2 & 1023;
    const int bx = rem & 31, by = rem >> 5;
    const float* in = (z == 0) ? qw : (z == 1) ? kw : (z == 2) ? vw : ow;
    bf16_t* o = WsT4 + ((size_t)z << 20);
    const int n0 = bx * 32, k0 = by * 32;
    const int xl = tid & 31, y4 = (tid >> 5) * 4;
#pragma unroll
    for (int i = 0; i < 4; ++i) {
      float v = in[(size_t)(k0 + y4 + i) * 1024 + n0 + xl];
      if (z == 3) v *= lng[k0 + y4 + i];
      tile[y4 + i][xl] = (bf16_t)v;
    }
    __syncthreads();
#pragma unroll
    for (int i = 0; i < 4; ++i)
      o[(size_t)(n0 + y4 + i) * 1024 + k0 + xl] = tile[xl][y4 + i];
    return;
  }
  const int pbid = bid - 11264;           // ---- prep vectors
  if (pbid >= 80) {
    const float4 z4 = {0.f, 0.f, 0.f, 0.f};
#pragma unroll
    for (int k = 0; k < 4; ++k) {
      ((float4*)ssum)[tid * 4 + k] = z4;
      ((float4*)ssq)[tid * 4 + k] = z4;
    }
    return;
  }
  const int jl = tid & 63, cq = tid >> 6;
  const int c0 = cq * 256;
  if (pbid < 48) {
    const int j = pbid * 64 + jl;
    const int s = j >> 10, jj = j & 1023;
    const float* w  = (s == 0) ? qw : (s == 1) ? kw : vw;
    const float* sb = (s == 0) ? qb : (s == 1) ? kb : vb;
    float acc = 0.f;
#pragma unroll 8
    for (int c = c0; c < c0 + 256; ++c)
      acc += cb[s * 1024 + c] * w[(size_t)c * 1024 + jj];
    part[cq][jl] = acc;
    __syncthreads();
    if (cq == 0)
      out_qkv[j] = part[0][jl] + part[1][jl] + part[2][jl] + part[3][jl] + sb[jj];
  } else {
    const int jj = (pbid - 48) * 64 + jl;  // [0,2048)
    const int col = jj & 1023;
    const float* coef = (jj < 1024) ? lng : lnb;
    float acc = 0.f;
#pragma unroll 8
    for (int c = c0; c < c0 + 256; ++c)
      acc += coef[c] * ow[(size_t)c * 1024 + col];
    part[cq][jl] = acc;
    __syncthreads();
    if (cq == 0) {
      const float tot = part[0][jl] + part[1][jl] + part[2][jl] + part[3][jl];
      if (jj < 1024) svec[col] = tot;
      else           c2v[col] = tot + outb[col];
    }
  }
}

// ---------------------------------------------------------------- v_frag
__global__ __launch_bounds__(256) void transpose_v(
    const bf16_t* __restrict__ qkvb, bf16_t* __restrict__ vfrag)
{
  __shared__ bf16_t tile[64][66];   // tile[f][key]
  const int bid = blockIdx.x;
  const int kb = bid & 15, bh = bid >> 4;
  const int b = bh >> 4, h = bh & 15;
  const int t = threadIdx.x;
  {
    const int key = t & 63, fc = (t >> 6) * 16;
    const bf16_t* src =
        qkvb + (size_t)(b * 1024 + kb * 64 + key) * 3072 + 2048 + h * 64 + fc;
    bf16x8 v0 = *(const bf16x8*)src;
    bf16x8 v1 = *(const bf16x8*)(src + 8);
#pragma unroll
    for (int j = 0; j < 8; ++j) {
      tile[fc + j][key]     = v0[j];
      tile[fc + 8 + j][key] = v1[j];
    }
  }
  __syncthreads();
#pragma unroll
  for (int ww = 0; ww < 2; ++ww) {
    const int g = t * 2 + ww;
    const int chunk = g >> 6;
    const int lane2 = g & 63;
    const int lr2 = lane2 & 15, lg2 = lane2 >> 4;
    const int kk = chunk >> 2, nf = chunk & 3;
    const int f = nf * 16 + lr2;
    const int key0 = kk * 32 + lg2 * 8;
    bf16x8 val;
#pragma unroll
    for (int j = 0; j < 8; ++j) val[j] = tile[f][key0 + j];
    *(bf16x8*)&vfrag[(((size_t)bh * 16 + kb) * 8 + chunk) * 512 + lane2 * 8] = val;
  }
}

// ---------------------------------------------------------------- GEMM (TMxTN)
// T2 swizzle (conflicts=0) + counted-vmcnt 3-buffer pipeline (r13-verified),
// tile = (32*TM) x (32*TN), 4 waves (2x2). LPS = loads/thread/stage.
template <typename OT, int TM, int TN>
__global__ __launch_bounds__(256) void gemm_bt_bias(
    const bf16_t* __restrict__ A, int lda,
    const bf16_t* __restrict__ Bt, int ldb,
    const float* __restrict__ bias,
    OT* __restrict__ C, int ldc,
    int K, int nTilesN, int blocksPerMat,
    int strideA, int strideB, int strideC, int xcdSwz)
{
  constexpr int TILEM = 32 * TM, TILEN = 32 * TN;
  constexpr int LPS = TM / 2 + TN / 2;
  __shared__ __align__(16) bf16_t As[3][TILEM * 32];
  __shared__ __align__(16) bf16_t Bs[3][TILEN * 32];
  int raw = blockIdx.x;
  if (xcdSwz) {
    const int cpx = gridDim.x >> 3;
    raw = (raw & 7) * cpx + (raw >> 3);
  }
  const int s   = raw / blocksPerMat;
  const int bid = raw % blocksPerMat;
  A  += (size_t)s * strideA;
  Bt += (size_t)s * strideB;
  C  += (size_t)s * strideC;
  const int mt = bid / nTilesN, nt = bid % nTilesN;
  const int m0 = mt * TILEM, n0 = nt * TILEN;
  const int tid = threadIdx.x;
  const int lane = tid & 63;
  const int lr = lane & 15, lg = lane >> 4;
  const int wid = tid >> 6;
  const int wr = wid >> 1, wc = wid & 1;
  const int sLg = lg ^ ((lr >> 1) & 3);

  f32x4 acc[TM][TN];
#pragma unroll
  for (int m = 0; m < TM; ++m)
#pragma unroll
    for (int n = 0; n < TN; ++n) acc[m][n] = (f32x4){0.f, 0.f, 0.f, 0.f};

  const int nk = K >> 5;

  auto stage = [&](int buf, int t) {
    const int k0 = t << 5;
#pragma unroll
    for (int p = 0; p < TM / 2; ++p) {
      const int c = p * 256 + tid;
      const int row = c >> 2;
      const int col = (((c & 3) ^ ((c >> 3) & 3)) << 3);
      async16(A + (size_t)(m0 + row) * lda + k0 + col, &As[buf][c * 8]);
    }
#pragma unroll
    for (int p = 0; p < TN / 2; ++p) {
      const int c = p * 256 + tid;
      const int row = c >> 2;
      const int col = (((c & 3) ^ ((c >> 3) & 3)) << 3);
      async16(Bt + (size_t)(n0 + row) * ldb + k0 + col, &Bs[buf][c * 8]);
    }
  };

  stage(0, 0);
  stage(1, 1);
  if constexpr (LPS == 4)
    asm volatile("s_waitcnt vmcnt(4)" ::: "memory");
  else if constexpr (LPS == 3)
    asm volatile("s_waitcnt vmcnt(3)" ::: "memory");
  else
    asm volatile("s_waitcnt vmcnt(2)" ::: "memory");
  __builtin_amdgcn_sched_barrier(0);
  __builtin_amdgcn_s_barrier();
  __builtin_amdgcn_sched_barrier(0);

  for (int t = 0; t < nk; ++t) {
    const int buf = t % 3;
    if (t + 2 < nk) stage((t + 2) % 3, t + 2);

    bf16x8 af[TM], bfr[TN];
#pragma unroll
    for (int m = 0; m < TM; ++m)
      af[m] = *(const bf16x8*)
          &As[buf][(wr * TM * 16 + m * 16 + lr) * 32 + sLg * 8];
#pragma unroll
    for (int n = 0; n < TN; ++n)
      bfr[n] = *(const bf16x8*)
          &Bs[buf][(wc * TN * 16 + n * 16 + lr) * 32 + sLg * 8];

    if (t + 2 < nk) {
      if constexpr (LPS == 4)
        asm volatile("s_waitcnt lgkmcnt(0) vmcnt(4)" ::: "memory");
      else if constexpr (LPS == 3)
        asm volatile("s_waitcnt lgkmcnt(0) vmcnt(3)" ::: "memory");
      else
        asm volatile("s_waitcnt lgkmcnt(0) vmcnt(2)" ::: "memory");
    } else {
      asm volatile("s_waitcnt lgkmcnt(0) vmcnt(0)" ::: "memory");
    }
    __builtin_amdgcn_sched_barrier(0);
    __builtin_amdgcn_s_barrier();
    __builtin_amdgcn_sched_barrier(0);

    __builtin_amdgcn_s_setprio(1);
#pragma unroll
    for (int m = 0; m < TM; ++m)
#pragma unroll
      for (int n = 0; n < TN; ++n)
        acc[m][n] = mfma_bf16(af[m], bfr[n], acc[m][n]);
    __builtin_amdgcn_s_setprio(0);
  }

#pragma unroll
  for (int n = 0; n < TN; ++n) {
    const int col = n0 + wc * TN * 16 + n * 16 + lr;
    const float bv = bias ? bias[col] : 0.0f;
#pragma unroll
    for (int m = 0; m < TM; ++m) {
      const int row = m0 + wr * TM * 16 + m * 16 + lg * 4;
#pragma unroll
      for (int r = 0; r < 4; ++r)
        C[(size_t)(row + r) * ldc + col] = (OT)(acc[m][n][r] + bv);
    }
  }
}

// ---------------------------------------------------------------- GEMM + LN
// Final projection with LayerNorm folded in (r15-verified math), 64x64 tiles
// (r17-verified: ~4/CU occupancy).
__global__ __launch_bounds__(256) void gemm_ln(
    const bf16_t* __restrict__ A, int lda,
    const bf16_t* __restrict__ Bt, int ldb,
    const float* __restrict__ svec, const float* __restrict__ c2v,
    const float* __restrict__ ssum, const float* __restrict__ ssq,
    float* __restrict__ C, int ldc, int K, int nTilesN)
{
  __shared__ __align__(16) bf16_t As[3][64 * 32];
  __shared__ __align__(16) bf16_t Bs[3][64 * 32];
  int raw = blockIdx.x;
  {
    const int cpx = gridDim.x >> 3;
    raw = (raw & 7) * cpx + (raw >> 3);
  }
  const int mt = raw / nTilesN, nt = raw % nTilesN;
  const int m0 = mt * 64, n0 = nt * 64;
  const int tid = threadIdx.x;
  const int lane = tid & 63;
  const int lr = lane & 15, lg = lane >> 4;
  const int wid = tid >> 6;
  const int wr = wid >> 1, wc = wid & 1;
  const int sLg = lg ^ ((lr >> 1) & 3);

  f32x4 acc[2][2];
#pragma unroll
  for (int m = 0; m < 2; ++m)
#pragma unroll
    for (int n = 0; n < 2; ++n) acc[m][n] = (f32x4){0.f, 0.f, 0.f, 0.f};

  const int nk = K >> 5;

  auto stage = [&](int buf, int t) {
    const int k0 = t << 5;
    const int c = tid;
    const int row = c >> 2;
    const int col = (((c & 3) ^ ((c >> 3) & 3)) << 3);
    async16(A + (size_t)(m0 + row) * lda + k0 + col, &As[buf][c * 8]);
    async16(Bt + (size_t)(n0 + row) * ldb + k0 + col, &Bs[buf][c * 8]);
  };

  stage(0, 0);
  stage(1, 1);
  asm volatile("s_waitcnt vmcnt(2)" ::: "memory");
  __builtin_amdgcn_sched_barrier(0);
  __builtin_amdgcn_s_barrier();
  __builtin_amdgcn_sched_barrier(0);

  for (int t = 0; t < nk; ++t) {
    const int buf = t % 3;
    if (t + 2 < nk) stage((t + 2) % 3, t + 2);

    bf16x8 af[2], bfr[2];
#pragma unroll
    for (int m = 0; m < 2; ++m)
      af[m] = *(const bf16x8*)&As[buf][(wr * 32 + m * 16 + lr) * 32 + sLg * 8];
#pragma unroll
    for (int n = 0; n < 2; ++n)
      bfr[n] = *(const bf16x8*)&Bs[buf][(wc * 32 + n * 16 + lr) * 32 + sLg * 8];

    if (t + 2 < nk)
      asm volatile("s_waitcnt lgkmcnt(0) vmcnt(2)" ::: "memory");
    else
      asm volatile("s_waitcnt lgkmcnt(0) vmcnt(0)" ::: "memory");
    __builtin_amdgcn_sched_barrier(0);
    __builtin_amdgcn_s_barrier();
    __builtin_amdgcn_sched_barrier(0);

    __builtin_amdgcn_s_setprio(1);
#pragma unroll
    for (int m = 0; m < 2; ++m)
#pragma unroll
      for (int n = 0; n < 2; ++n)
        acc[m][n] = mfma_bf16(af[m], bfr[n], acc[m][n]);
    __builtin_amdgcn_s_setprio(0);
  }

#pragma unroll
  for (int n = 0; n < 2; ++n) {
    const int col = n0 + wc * 32 + n * 16 + lr;
    const float sj = svec[col];
    const float c2 = c2v[col];
#pragma unroll
    for (int m = 0; m < 2; ++m) {
      const int row = m0 + wr * 32 + m * 16 + lg * 4;
      const float* s1 = &ssum[row];
      const float* s2 = &ssq[row];
#pragma unroll
      for (int r = 0; r < 4; ++r) {
        const float mu  = s1[r] * (1.0f / 1024.0f);
        const float var = s2[r] * (1.0f / 1024.0f) - mu * mu;
        const float al  = rsqrtf(var + 1e-5f);
        C[(size_t)(row + r) * ldc + col] = al * acc[m][n][r] - al * mu * sj + c2;
      }
    }
  }
}

// ---------------------------------------------------------------- attention
// LDS-staged flash attention (r9-verified) + per-row stats atomics (r15).
// Pair-balanced: 512 blocks, block = band pair (slot, 15-slot) = 17 tiles
// (r18-verified best: equal per-block lifetime beats nominal residency).
__global__ __launch_bounds__(256) void attn_kernel(
    const bf16_t* __restrict__ qkv, const bf16_t* __restrict__ vfrag,
    bf16_t* __restrict__ o, float* __restrict__ ssum, float* __restrict__ ssq)
{
  __shared__ __align__(16) bf16_t Ks[2][8][512];
  __shared__ __align__(16) bf16_t Vs[2][8][512];
  __shared__ __align__(16) bf16_t Ps[4][16][72];
  const int LD = 3072;
  const bf16_t* q = qkv;
  const bf16_t* k = qkv + 1024;

  const int raw = blockIdx.x;
  const int xcd = raw & 7, idx = raw >> 3;
  const int bh   = (idx >> 3) * 8 + xcd;
  const int slot = idx & 7;
  const int b = bh >> 4, h = bh & 15;

  const int tid = threadIdx.x;
  const int lane = tid & 63;
  const int lr = lane & 15, lg = lane >> 4;
  const int w = tid >> 6;

  const bf16_t* kbase = k + (size_t)(b * T_) * LD + h * 64;
  const bf16_t* vfbase = vfrag + (size_t)bh * 16 * 8 * 512;

  auto stage = [&](int bf, int it) {
    const int kv0 = it << 6;
#pragma unroll
    for (int cc = 0; cc < 4; ++cc) {
      const int c = w * 4 + cc;
      if (c < 8) {
        const int kg = c >> 1, kk = c & 1;
        async16(kbase + (size_t)(kv0 + kg * 16 + lr) * LD + kk * 32 + lg * 8,
                &Ks[bf][c][lane * 8]);
      } else {
        const int cv = c - 8;
        async16(vfbase + ((size_t)it * 8 + cv) * 512 + lane * 8,
                &Vs[bf][cv][lane * 8]);
      }
    }
  };

#pragma unroll
  for (int pass = 0; pass < 2; ++pass) {
    const int band = pass ? (15 - slot) : slot;
    const int myq = band * 64 + w * 16 + lr;
    const int nIter = band + 1;

    bf16x8 qf[2];
    {
      const size_t qr = (size_t)(b * T_ + myq) * LD + h * 64;
      qf[0] = *(const bf16x8*)&q[qr + lg * 8];
      qf[1] = *(const bf16x8*)&q[qr + 32 + lg * 8];
    }

    float mi = -3.0e38f, li = 0.0f;
    f32x4 acc[4];
#pragma unroll
    for (int nf = 0; nf < 4; ++nf) acc[nf] = (f32x4){0.f, 0.f, 0.f, 0.f};

    stage(0, 0);
    __syncthreads();

    for (int it = 0; it < nIter; ++it) {
      const int bf = it & 1;
      if (it + 1 < nIter) stage(bf ^ 1, it + 1);
      const int kv0 = it << 6;

      f32x4 sfr[4];
      __builtin_amdgcn_s_setprio(1);
#pragma unroll
      for (int kg = 0; kg < 4; ++kg) {
        bf16x8 kf0 = *(const bf16x8*)&Ks[bf][kg * 2 + 0][lane * 8];
        bf16x8 kf1 = *(const bf16x8*)&Ks[bf][kg * 2 + 1][lane * 8];
        f32x4 z = (f32x4){0.f, 0.f, 0.f, 0.f};
        z = mfma_bf16(kf0, qf[0], z);
        z = mfma_bf16(kf1, qf[1], z);
        sfr[kg] = z;
      }
      __builtin_amdgcn_s_setprio(0);

      float sv[4][4];
      float pm[4];
#pragma unroll
      for (int kg = 0; kg < 4; ++kg) {
        const int keyb = kv0 + kg * 16 + lg * 4;
        pm[kg] = -3.0e38f;
#pragma unroll
        for (int r = 0; r < 4; ++r) {
          float xx = sfr[kg][r] * 0.015625f;
          if (keyb + r > myq) xx = -3.0e38f;
          sv[kg][r] = xx;
          pm[kg] = fmaxf(pm[kg], xx);
        }
      }
      float pmax = fmaxf(fmaxf(pm[0], pm[1]), fmaxf(pm[2], pm[3]));
      pmax = fmaxf(pmax, __shfl_xor(pmax, 16));
      pmax = fmaxf(pmax, __shfl_xor(pmax, 32));
      const float mnew = fmaxf(mi, pmax);
      const float fr = __expf(mi - mnew);
      mi = mnew;
      float ps[4];
#pragma unroll
      for (int kg = 0; kg < 4; ++kg) {
        float p0 = __expf(sv[kg][0] - mi);
        float p1 = __expf(sv[kg][1] - mi);
        float p2 = __expf(sv[kg][2] - mi);
        float p3 = __expf(sv[kg][3] - mi);
        sv[kg][0] = p0; sv[kg][1] = p1; sv[kg][2] = p2; sv[kg][3] = p3;
        ps[kg] = (p0 + p1) + (p2 + p3);
      }
      float psum = (ps[0] + ps[1]) + (ps[2] + ps[3]);
      psum += __shfl_xor(psum, 16);
      psum += __shfl_xor(psum, 32);
      li = li * fr + psum;
#pragma unroll
      for (int nf = 0; nf < 4; ++nf)
#pragma unroll
        for (int r = 0; r < 4; ++r) acc[nf][r] *= fr;

#pragma unroll
      for (int kg = 0; kg < 4; ++kg) {
        bf16x4 p4;
#pragma unroll
        for (int r = 0; r < 4; ++r) p4[r] = (bf16_t)sv[kg][r];
        *(bf16x4*)&Ps[w][lr][kg * 16 + lg * 4] = p4;
      }

      __builtin_amdgcn_s_setprio(1);
#pragma unroll
      for (int kk = 0; kk < 2; ++kk) {
        bf16x8 pf = *(const bf16x8*)&Ps[w][lr][kk * 32 + lg * 8];
#pragma unroll
        for (int nf = 0; nf < 4; ++nf) {
          bf16x8 vf = *(const bf16x8*)&Vs[bf][kk * 4 + nf][lane * 8];
          acc[nf] = mfma_bf16(vf, pf, acc[nf]);
        }
      }
      __builtin_amdgcn_s_setprio(0);

      __syncthreads();
    }

    const float inv = 1.0f / li;
    float st1 = 0.f, st2 = 0.f;
#pragma unroll
    for (int nf = 0; nf < 4; ++nf) {
      bf16x4 o4;
#pragma unroll
      for (int r = 0; r < 4; ++r) {
        const float ov = acc[nf][r] * inv;
        o4[r] = (bf16_t)ov;
        st1 += ov;
        st2 += ov * ov;
      }
      *(bf16x4*)&o[(size_t)(b * T_ + myq) * C_ + h * 64 + nf * 16 + lg * 4] = o4;
    }
    st1 += __shfl_xor(st1, 16); st1 += __shfl_xor(st1, 32);
    st2 += __shfl_xor(st2, 16); st2 += __shfl_xor(st2, 32);
    if (lg == 0) {
      atomicAdd(&ssum[b * T_ + myq], st1);
      atomicAdd(&ssq[b * T_ + myq], st2);
    }
  }
}

// ---------------------------------------------------------------- launch
extern "C" void kernel_launch(void* const* d_in, const int* in_sizes, int n_in,
                              void* d_out, int out_size, void* d_ws, size_t ws_size,
                              hipStream_t stream)
{
  const float* x        = (const float*)d_in[0];
  const float* c_attn_w = (const float*)d_in[1];
  const float* c_attn_b = (const float*)d_in[2];
  const float* q_w      = (const float*)d_in[3];
  const float* q_b      = (const float*)d_in[4];
  const float* k_w      = (const float*)d_in[5];
  const float* k_b      = (const float*)d_in[6];
  const float* v_w      = (const float*)d_in[7];
  const float* v_b      = (const float*)d_in[8];
  const float* ln_g     = (const float*)d_in[9];
  const float* ln_b     = (const float*)d_in[10];
  const float* out_w    = (const float*)d_in[11];
  const float* out_b    = (const float*)d_in[12];

  char* ws = (char*)d_ws;
  bf16_t* qkvb      = (bf16_t*)(ws + 0);          // [4096][3072]
  bf16_t* xb        = (bf16_t*)(ws + 25165824);   // [4096][1024] dead after qkv
  bf16_t* ob        = (bf16_t*)(ws + 25165824);   // attn output (overlays xb)
  bf16_t* WsT4      = (bf16_t*)(ws + 33554432);   // 4 slabs of 1M bf16
  bf16_t* c_attn_wb = (bf16_t*)(ws + 41943040);   // [1024][3072]
  bf16_t* Wt_eff    = (bf16_t*)(ws + 48234496);   // [3072][1024]
  float*  bias_eff  = (float*)(ws + 54525952);    // [3072]
  bf16_t* vfrag     = (bf16_t*)(ws + 54538240);   // 8 MB fragment-linear V
  float*  ssum      = (float*)(ws + 62926848);    // [4096]
  float*  ssq       = (float*)(ws + 62943232);    // [4096]
  float*  svec      = (float*)(ws + 62959616);    // [1024]
  float*  c2v       = (float*)(ws + 62963712);    // [1024]

  prep_all<<<dim3(11345), 256, 0, stream>>>(
      x, xb, c_attn_w, c_attn_wb,
      q_w, k_w, v_w, out_w, ln_g, WsT4,
      c_attn_b, q_b, k_b, v_b, ln_b, out_b,
      bias_eff, svec, c2v, ssum, ssq);

  // fused weights: 64x64 tiles, 768 blocks (r16-verified)
  gemm_bt_bias<bf16_t, 2, 2><<<dim3(768), 256, 0, stream>>>(
      WsT4, 1024, c_attn_wb, 3072, nullptr, Wt_eff, 1024,
      1024, 16, 256, 1 << 20, 1024, 1 << 20, 1);

  // qkvb = xb @ Wt_eff^T + bias_eff (128x128, 768 blocks — r16-verified best)
  gemm_bt_bias<bf16_t, 4, 4><<<dim3(768), 256, 0, stream>>>(
      xb, 1024, Wt_eff, 1024, bias_eff, qkvb, 3072, 1024, 24, 768, 0, 0, 0, 1);

  transpose_v<<<dim3(1024), 256, 0, stream>>>(qkvb, vfrag);

  // attention: 512 pair-balanced blocks (r18-verified best)
  attn_kernel<<<dim3(512), 256, 0, stream>>>(qkvb, vfrag, ob, ssum, ssq);

  // final GEMM+LN: 64x64 tiles, 1024 blocks (r17-verified)
  gemm_ln<<<dim3(1024), 256, 0, stream>>>(
      ob, 1024, WsT4 + (size_t)3 * (1 << 20), 1024,
      svec, c2v, ssum, ssq, (float*)d_out, 1024, 1024, 16);
}

// Round 21
// 137.694 us; speedup vs baseline: 1.0701x; 1.0065x over previous
//
#include <hip/hip_runtime.h>
#include <hip/hip_bf16.h>
#include <stdint.h>

typedef __bf16 bf16_t;
typedef bf16_t bf16x4 __attribute__((ext_vector_type(4)));
typedef bf16_t bf16x8 __attribute__((ext_vector_type(8)));
typedef float  f32x4  __attribute__((ext_vector_type(4)));

#define B_   4
#define T_   1024
#define C_   1024
#define H_   16

__device__ __forceinline__ f32x4 mfma_bf16(bf16x8 a, bf16x8 b, f32x4 c) {
  return __builtin_amdgcn_mfma_f32_16x16x32_bf16(a, b, c, 0, 0, 0);
}

__device__ __forceinline__ void async16(const bf16_t* g, bf16_t* l) {
  __builtin_amdgcn_global_load_lds(
      (__attribute__((address_space(1))) void*)(uintptr_t)g,
      (__attribute__((address_space(3))) void*)l, 16, 0, 0);
}

// ---------------------------------------------------------------- prep_all
// One launch, block-range dispatch (r16-verified):
//   [0,7168)      : f32->bf16 convert of x + c_attn_w
//   [7168,11264)  : 4-slab weight transpose (slab3 = (ln_g ⊙ out_w)^T)
//   [11264,11345) : qkv effective bias / svec / c2v / zero ssum+ssq
__global__ __launch_bounds__(256) void prep_all(
    const float* __restrict__ x, bf16_t* __restrict__ xb,
    const float* __restrict__ caw, bf16_t* __restrict__ cawb,
    const float* __restrict__ qw, const float* __restrict__ kw,
    const float* __restrict__ vw, const float* __restrict__ ow,
    const float* __restrict__ lng, bf16_t* __restrict__ WsT4,
    const float* __restrict__ cb,
    const float* __restrict__ qb, const float* __restrict__ kb,
    const float* __restrict__ vb,
    const float* __restrict__ lnb, const float* __restrict__ outb,
    float* __restrict__ out_qkv, float* __restrict__ svec,
    float* __restrict__ c2v, float* __restrict__ ssum, float* __restrict__ ssq)
{
  __shared__ bf16_t tile[32][33];
  __shared__ float part[4][64];
  const int bid = blockIdx.x;
  const int tid = threadIdx.x;

  if (bid < 7168) {                       // ---- convert
    const int i = bid * 256 + tid;
    const float* src; bf16_t* dst; int idx;
    if (i < 1048576) { src = x; dst = xb; idx = i; }
    else { src = caw; dst = cawb; idx = i - 1048576; }
    const float4 v = *(const float4*)(src + (size_t)idx * 4);
    bf16x4 o;
    o[0] = (bf16_t)v.x; o[1] = (bf16_t)v.y; o[2] = (bf16_t)v.z; o[3] = (bf16_t)v.w;
    *(bf16x4*)(dst + (size_t)idx * 4) = o;
    return;
  }
  if (bid < 11264) {                      // ---- transpose 4 slabs
    const int b2 = bid - 7168;
    const int z = b2 >> 10, rem = b2 & 1023;
    const int bx = rem & 31, by = rem >> 5;
    const float* in = (z == 0) ? qw : (z == 1) ? kw : (z == 2) ? vw : ow;
    bf16_t* o = WsT4 + ((size_t)z << 20);
    const int n0 = bx * 32, k0 = by * 32;
    const int xl = tid & 31, y4 = (tid >> 5) * 4;
#pragma unroll
    for (int i = 0; i < 4; ++i) {
      float v = in[(size_t)(k0 + y4 + i) * 1024 + n0 + xl];
      if (z == 3) v *= lng[k0 + y4 + i];
      tile[y4 + i][xl] = (bf16_t)v;
    }
    __syncthreads();
#pragma unroll
    for (int i = 0; i < 4; ++i)
      o[(size_t)(n0 + y4 + i) * 1024 + k0 + xl] = tile[xl][y4 + i];
    return;
  }
  const int pbid = bid - 11264;           // ---- prep vectors
  if (pbid >= 80) {
    const float4 z4 = {0.f, 0.f, 0.f, 0.f};
#pragma unroll
    for (int k = 0; k < 4; ++k) {
      ((float4*)ssum)[tid * 4 + k] = z4;
      ((float4*)ssq)[tid * 4 + k] = z4;
    }
    return;
  }
  const int jl = tid & 63, cq = tid >> 6;
  const int c0 = cq * 256;
  if (pbid < 48) {
    const int j = pbid * 64 + jl;
    const int s = j >> 10, jj = j & 1023;
    const float* w  = (s == 0) ? qw : (s == 1) ? kw : vw;
    const float* sb = (s == 0) ? qb : (s == 1) ? kb : vb;
    float acc = 0.f;
#pragma unroll 8
    for (int c = c0; c < c0 + 256; ++c)
      acc += cb[s * 1024 + c] * w[(size_t)c * 1024 + jj];
    part[cq][jl] = acc;
    __syncthreads();
    if (cq == 0)
      out_qkv[j] = part[0][jl] + part[1][jl] + part[2][jl] + part[3][jl] + sb[jj];
  } else {
    const int jj = (pbid - 48) * 64 + jl;  // [0,2048)
    const int col = jj & 1023;
    const float* coef = (jj < 1024) ? lng : lnb;
    float acc = 0.f;
#pragma unroll 8
    for (int c = c0; c < c0 + 256; ++c)
      acc += coef[c] * ow[(size_t)c * 1024 + col];
    part[cq][jl] = acc;
    __syncthreads();
    if (cq == 0) {
      const float tot = part[0][jl] + part[1][jl] + part[2][jl] + part[3][jl];
      if (jj < 1024) svec[col] = tot;
      else           c2v[col] = tot + outb[col];
    }
  }
}

// ---------------------------------------------------------------- v_frag
__global__ __launch_bounds__(256) void transpose_v(
    const bf16_t* __restrict__ qkvb, bf16_t* __restrict__ vfrag)
{
  __shared__ bf16_t tile[64][66];   // tile[f][key]
  const int bid = blockIdx.x;
  const int kb = bid & 15, bh = bid >> 4;
  const int b = bh >> 4, h = bh & 15;
  const int t = threadIdx.x;
  {
    const int key = t & 63, fc = (t >> 6) * 16;
    const bf16_t* src =
        qkvb + (size_t)(b * 1024 + kb * 64 + key) * 3072 + 2048 + h * 64 + fc;
    bf16x8 v0 = *(const bf16x8*)src;
    bf16x8 v1 = *(const bf16x8*)(src + 8);
#pragma unroll
    for (int j = 0; j < 8; ++j) {
      tile[fc + j][key]     = v0[j];
      tile[fc + 8 + j][key] = v1[j];
    }
  }
  __syncthreads();
#pragma unroll
  for (int ww = 0; ww < 2; ++ww) {
    const int g = t * 2 + ww;
    const int chunk = g >> 6;
    const int lane2 = g & 63;
    const int lr2 = lane2 & 15, lg2 = lane2 >> 4;
    const int kk = chunk >> 2, nf = chunk & 3;
    const int f = nf * 16 + lr2;
    const int key0 = kk * 32 + lg2 * 8;
    bf16x8 val;
#pragma unroll
    for (int j = 0; j < 8; ++j) val[j] = tile[f][key0 + j];
    *(bf16x8*)&vfrag[(((size_t)bh * 16 + kb) * 8 + chunk) * 512 + lane2 * 8] = val;
  }
}

// ---------------------------------------------------------------- GEMM (TMxTN)
// T2 swizzle (conflicts=0) + counted-vmcnt 3-buffer pipeline (r13-verified),
// tile = (32*TM) x (32*TN), 4 waves (2x2). LPS = loads/thread/stage.
template <typename OT, int TM, int TN>
__global__ __launch_bounds__(256) void gemm_bt_bias(
    const bf16_t* __restrict__ A, int lda,
    const bf16_t* __restrict__ Bt, int ldb,
    const float* __restrict__ bias,
    OT* __restrict__ C, int ldc,
    int K, int nTilesN, int blocksPerMat,
    int strideA, int strideB, int strideC, int xcdSwz)
{
  constexpr int TILEM = 32 * TM, TILEN = 32 * TN;
  constexpr int LPS = TM / 2 + TN / 2;
  __shared__ __align__(16) bf16_t As[3][TILEM * 32];
  __shared__ __align__(16) bf16_t Bs[3][TILEN * 32];
  int raw = blockIdx.x;
  if (xcdSwz) {
    const int cpx = gridDim.x >> 3;
    raw = (raw & 7) * cpx + (raw >> 3);
  }
  const int s   = raw / blocksPerMat;
  const int bid = raw % blocksPerMat;
  A  += (size_t)s * strideA;
  Bt += (size_t)s * strideB;
  C  += (size_t)s * strideC;
  const int mt = bid / nTilesN, nt = bid % nTilesN;
  const int m0 = mt * TILEM, n0 = nt * TILEN;
  const int tid = threadIdx.x;
  const int lane = tid & 63;
  const int lr = lane & 15, lg = lane >> 4;
  const int wid = tid >> 6;
  const int wr = wid >> 1, wc = wid & 1;
  const int sLg = lg ^ ((lr >> 1) & 3);

  f32x4 acc[TM][TN];
#pragma unroll
  for (int m = 0; m < TM; ++m)
#pragma unroll
    for (int n = 0; n < TN; ++n) acc[m][n] = (f32x4){0.f, 0.f, 0.f, 0.f};

  const int nk = K >> 5;

  auto stage = [&](int buf, int t) {
    const int k0 = t << 5;
#pragma unroll
    for (int p = 0; p < TM / 2; ++p) {
      const int c = p * 256 + tid;
      const int row = c >> 2;
      const int col = (((c & 3) ^ ((c >> 3) & 3)) << 3);
      async16(A + (size_t)(m0 + row) * lda + k0 + col, &As[buf][c * 8]);
    }
#pragma unroll
    for (int p = 0; p < TN / 2; ++p) {
      const int c = p * 256 + tid;
      const int row = c >> 2;
      const int col = (((c & 3) ^ ((c >> 3) & 3)) << 3);
      async16(Bt + (size_t)(n0 + row) * ldb + k0 + col, &Bs[buf][c * 8]);
    }
  };

  stage(0, 0);
  stage(1, 1);
  if constexpr (LPS == 4)
    asm volatile("s_waitcnt vmcnt(4)" ::: "memory");
  else if constexpr (LPS == 3)
    asm volatile("s_waitcnt vmcnt(3)" ::: "memory");
  else
    asm volatile("s_waitcnt vmcnt(2)" ::: "memory");
  __builtin_amdgcn_sched_barrier(0);
  __builtin_amdgcn_s_barrier();
  __builtin_amdgcn_sched_barrier(0);

  for (int t = 0; t < nk; ++t) {
    const int buf = t % 3;
    if (t + 2 < nk) stage((t + 2) % 3, t + 2);

    bf16x8 af[TM], bfr[TN];
#pragma unroll
    for (int m = 0; m < TM; ++m)
      af[m] = *(const bf16x8*)
          &As[buf][(wr * TM * 16 + m * 16 + lr) * 32 + sLg * 8];
#pragma unroll
    for (int n = 0; n < TN; ++n)
      bfr[n] = *(const bf16x8*)
          &Bs[buf][(wc * TN * 16 + n * 16 + lr) * 32 + sLg * 8];

    if (t + 2 < nk) {
      if constexpr (LPS == 4)
        asm volatile("s_waitcnt lgkmcnt(0) vmcnt(4)" ::: "memory");
      else if constexpr (LPS == 3)
        asm volatile("s_waitcnt lgkmcnt(0) vmcnt(3)" ::: "memory");
      else
        asm volatile("s_waitcnt lgkmcnt(0) vmcnt(2)" ::: "memory");
    } else {
      asm volatile("s_waitcnt lgkmcnt(0) vmcnt(0)" ::: "memory");
    }
    __builtin_amdgcn_sched_barrier(0);
    __builtin_amdgcn_s_barrier();
    __builtin_amdgcn_sched_barrier(0);

    __builtin_amdgcn_s_setprio(1);
#pragma unroll
    for (int m = 0; m < TM; ++m)
#pragma unroll
      for (int n = 0; n < TN; ++n)
        acc[m][n] = mfma_bf16(af[m], bfr[n], acc[m][n]);
    __builtin_amdgcn_s_setprio(0);
  }

#pragma unroll
  for (int n = 0; n < TN; ++n) {
    const int col = n0 + wc * TN * 16 + n * 16 + lr;
    const float bv = bias ? bias[col] : 0.0f;
#pragma unroll
    for (int m = 0; m < TM; ++m) {
      const int row = m0 + wr * TM * 16 + m * 16 + lg * 4;
#pragma unroll
      for (int r = 0; r < 4; ++r)
        C[(size_t)(row + r) * ldc + col] = (OT)(acc[m][n][r] + bv);
    }
  }
}

// ---------------------------------------------------------------- GEMM + LN
// Final projection with LayerNorm folded in (r15-verified math), 64x64 tiles
// (r17-verified: ~4/CU occupancy).
__global__ __launch_bounds__(256) void gemm_ln(
    const bf16_t* __restrict__ A, int lda,
    const bf16_t* __restrict__ Bt, int ldb,
    const float* __restrict__ svec, const float* __restrict__ c2v,
    const float* __restrict__ ssum, const float* __restrict__ ssq,
    float* __restrict__ C, int ldc, int K, int nTilesN)
{
  __shared__ __align__(16) bf16_t As[3][64 * 32];
  __shared__ __align__(16) bf16_t Bs[3][64 * 32];
  int raw = blockIdx.x;
  {
    const int cpx = gridDim.x >> 3;
    raw = (raw & 7) * cpx + (raw >> 3);
  }
  const int mt = raw / nTilesN, nt = raw % nTilesN;
  const int m0 = mt * 64, n0 = nt * 64;
  const int tid = threadIdx.x;
  const int lane = tid & 63;
  const int lr = lane & 15, lg = lane >> 4;
  const int wid = tid >> 6;
  const int wr = wid >> 1, wc = wid & 1;
  const int sLg = lg ^ ((lr >> 1) & 3);

  f32x4 acc[2][2];
#pragma unroll
  for (int m = 0; m < 2; ++m)
#pragma unroll
    for (int n = 0; n < 2; ++n) acc[m][n] = (f32x4){0.f, 0.f, 0.f, 0.f};

  const int nk = K >> 5;

  auto stage = [&](int buf, int t) {
    const int k0 = t << 5;
    const int c = tid;
    const int row = c >> 2;
    const int col = (((c & 3) ^ ((c >> 3) & 3)) << 3);
    async16(A + (size_t)(m0 + row) * lda + k0 + col, &As[buf][c * 8]);
    async16(Bt + (size_t)(n0 + row) * ldb + k0 + col, &Bs[buf][c * 8]);
  };

  stage(0, 0);
  stage(1, 1);
  asm volatile("s_waitcnt vmcnt(2)" ::: "memory");
  __builtin_amdgcn_sched_barrier(0);
  __builtin_amdgcn_s_barrier();
  __builtin_amdgcn_sched_barrier(0);

  for (int t = 0; t < nk; ++t) {
    const int buf = t % 3;
    if (t + 2 < nk) stage((t + 2) % 3, t + 2);

    bf16x8 af[2], bfr[2];
#pragma unroll
    for (int m = 0; m < 2; ++m)
      af[m] = *(const bf16x8*)&As[buf][(wr * 32 + m * 16 + lr) * 32 + sLg * 8];
#pragma unroll
    for (int n = 0; n < 2; ++n)
      bfr[n] = *(const bf16x8*)&Bs[buf][(wc * 32 + n * 16 + lr) * 32 + sLg * 8];

    if (t + 2 < nk)
      asm volatile("s_waitcnt lgkmcnt(0) vmcnt(2)" ::: "memory");
    else
      asm volatile("s_waitcnt lgkmcnt(0) vmcnt(0)" ::: "memory");
    __builtin_amdgcn_sched_barrier(0);
    __builtin_amdgcn_s_barrier();
    __builtin_amdgcn_sched_barrier(0);

    __builtin_amdgcn_s_setprio(1);
#pragma unroll
    for (int m = 0; m < 2; ++m)
#pragma unroll
      for (int n = 0; n < 2; ++n)
        acc[m][n] = mfma_bf16(af[m], bfr[n], acc[m][n]);
    __builtin_amdgcn_s_setprio(0);
  }

#pragma unroll
  for (int n = 0; n < 2; ++n) {
    const int col = n0 + wc * 32 + n * 16 + lr;
    const float sj = svec[col];
    const float c2 = c2v[col];
#pragma unroll
    for (int m = 0; m < 2; ++m) {
      const int row = m0 + wr * 32 + m * 16 + lg * 4;
      const float* s1 = &ssum[row];
      const float* s2 = &ssq[row];
#pragma unroll
      for (int r = 0; r < 4; ++r) {
        const float mu  = s1[r] * (1.0f / 1024.0f);
        const float var = s2[r] * (1.0f / 1024.0f) - mu * mu;
        const float al  = rsqrtf(var + 1e-5f);
        C[(size_t)(row + r) * ldc + col] = al * acc[m][n][r] - al * mu * sj + c2;
      }
    }
  }
}

// ---------------------------------------------------------------- attention
// LDS-staged flash attention (r9-verified) + stats atomics (r15),
// pair-balanced 512 blocks (r18-verified best) + T13 defer-max: skip the
// O-rescale when all 16 rows in the wave have pmax <= mi + 8 (wave-uniform
// branch via __all; P bounded by e^8, li scales identically -> O exact).
__global__ __launch_bounds__(256) void attn_kernel(
    const bf16_t* __restrict__ qkv, const bf16_t* __restrict__ vfrag,
    bf16_t* __restrict__ o, float* __restrict__ ssum, float* __restrict__ ssq)
{
  __shared__ __align__(16) bf16_t Ks[2][8][512];
  __shared__ __align__(16) bf16_t Vs[2][8][512];
  __shared__ __align__(16) bf16_t Ps[4][16][72];
  const int LD = 3072;
  const bf16_t* q = qkv;
  const bf16_t* k = qkv + 1024;

  const int raw = blockIdx.x;
  const int xcd = raw & 7, idx = raw >> 3;
  const int bh   = (idx >> 3) * 8 + xcd;
  const int slot = idx & 7;
  const int b = bh >> 4, h = bh & 15;

  const int tid = threadIdx.x;
  const int lane = tid & 63;
  const int lr = lane & 15, lg = lane >> 4;
  const int w = tid >> 6;

  const bf16_t* kbase = k + (size_t)(b * T_) * LD + h * 64;
  const bf16_t* vfbase = vfrag + (size_t)bh * 16 * 8 * 512;

  auto stage = [&](int bf, int it) {
    const int kv0 = it << 6;
#pragma unroll
    for (int cc = 0; cc < 4; ++cc) {
      const int c = w * 4 + cc;
      if (c < 8) {
        const int kg = c >> 1, kk = c & 1;
        async16(kbase + (size_t)(kv0 + kg * 16 + lr) * LD + kk * 32 + lg * 8,
                &Ks[bf][c][lane * 8]);
      } else {
        const int cv = c - 8;
        async16(vfbase + ((size_t)it * 8 + cv) * 512 + lane * 8,
                &Vs[bf][cv][lane * 8]);
      }
    }
  };

#pragma unroll
  for (int pass = 0; pass < 2; ++pass) {
    const int band = pass ? (15 - slot) : slot;
    const int myq = band * 64 + w * 16 + lr;
    const int nIter = band + 1;

    bf16x8 qf[2];
    {
      const size_t qr = (size_t)(b * T_ + myq) * LD + h * 64;
      qf[0] = *(const bf16x8*)&q[qr + lg * 8];
      qf[1] = *(const bf16x8*)&q[qr + 32 + lg * 8];
    }

    float mi = -3.0e38f, li = 0.0f;
    f32x4 acc[4];
#pragma unroll
    for (int nf = 0; nf < 4; ++nf) acc[nf] = (f32x4){0.f, 0.f, 0.f, 0.f};

    stage(0, 0);
    __syncthreads();

    for (int it = 0; it < nIter; ++it) {
      const int bf = it & 1;
      if (it + 1 < nIter) stage(bf ^ 1, it + 1);
      const int kv0 = it << 6;

      f32x4 sfr[4];
      __builtin_amdgcn_s_setprio(1);
#pragma unroll
      for (int kg = 0; kg < 4; ++kg) {
        bf16x8 kf0 = *(const bf16x8*)&Ks[bf][kg * 2 + 0][lane * 8];
        bf16x8 kf1 = *(const bf16x8*)&Ks[bf][kg * 2 + 1][lane * 8];
        f32x4 z = (f32x4){0.f, 0.f, 0.f, 0.f};
        z = mfma_bf16(kf0, qf[0], z);
        z = mfma_bf16(kf1, qf[1], z);
        sfr[kg] = z;
      }
      __builtin_amdgcn_s_setprio(0);

      float sv[4][4];
      float pm[4];
#pragma unroll
      for (int kg = 0; kg < 4; ++kg) {
        const int keyb = kv0 + kg * 16 + lg * 4;
        pm[kg] = -3.0e38f;
#pragma unroll
        for (int r = 0; r < 4; ++r) {
          float xx = sfr[kg][r] * 0.015625f;
          if (keyb + r > myq) xx = -3.0e38f;
          sv[kg][r] = xx;
          pm[kg] = fmaxf(pm[kg], xx);
        }
      }
      float pmax = fmaxf(fmaxf(pm[0], pm[1]), fmaxf(pm[2], pm[3]));
      pmax = fmaxf(pmax, __shfl_xor(pmax, 16));
      pmax = fmaxf(pmax, __shfl_xor(pmax, 32));
      // T13 defer-max: only rescale when some row's max grew past mi + 8
      if (!__all(pmax <= mi + 8.0f)) {
        const float mnew = fmaxf(mi, pmax);
        const float fr = __expf(mi - mnew);
        mi = mnew;
        li *= fr;
#pragma unroll
        for (int nf = 0; nf < 4; ++nf)
#pragma unroll
          for (int r = 0; r < 4; ++r) acc[nf][r] *= fr;
      }
      float ps[4];
#pragma unroll
      for (int kg = 0; kg < 4; ++kg) {
        float p0 = __expf(sv[kg][0] - mi);
        float p1 = __expf(sv[kg][1] - mi);
        float p2 = __expf(sv[kg][2] - mi);
        float p3 = __expf(sv[kg][3] - mi);
        sv[kg][0] = p0; sv[kg][1] = p1; sv[kg][2] = p2; sv[kg][3] = p3;
        ps[kg] = (p0 + p1) + (p2 + p3);
      }
      float psum = (ps[0] + ps[1]) + (ps[2] + ps[3]);
      psum += __shfl_xor(psum, 16);
      psum += __shfl_xor(psum, 32);
      li += psum;

#pragma unroll
      for (int kg = 0; kg < 4; ++kg) {
        bf16x4 p4;
#pragma unroll
        for (int r = 0; r < 4; ++r) p4[r] = (bf16_t)sv[kg][r];
        *(bf16x4*)&Ps[w][lr][kg * 16 + lg * 4] = p4;
      }

      __builtin_amdgcn_s_setprio(1);
#pragma unroll
      for (int kk = 0; kk < 2; ++kk) {
        bf16x8 pf = *(const bf16x8*)&Ps[w][lr][kk * 32 + lg * 8];
#pragma unroll
        for (int nf = 0; nf < 4; ++nf) {
          bf16x8 vf = *(const bf16x8*)&Vs[bf][kk * 4 + nf][lane * 8];
          acc[nf] = mfma_bf16(vf, pf, acc[nf]);
        }
      }
      __builtin_amdgcn_s_setprio(0);

      __syncthreads();
    }

    const float inv = 1.0f / li;
    float st1 = 0.f, st2 = 0.f;
#pragma unroll
    for (int nf = 0; nf < 4; ++nf) {
      bf16x4 o4;
#pragma unroll
      for (int r = 0; r < 4; ++r) {
        const float ov = acc[nf][r] * inv;
        o4[r] = (bf16_t)ov;
        st1 += ov;
        st2 += ov * ov;
      }
      *(bf16x4*)&o[(size_t)(b * T_ + myq) * C_ + h * 64 + nf * 16 + lg * 4] = o4;
    }
    st1 += __shfl_xor(st1, 16); st1 += __shfl_xor(st1, 32);
    st2 += __shfl_xor(st2, 16); st2 += __shfl_xor(st2, 32);
    if (lg == 0) {
      atomicAdd(&ssum[b * T_ + myq], st1);
      atomicAdd(&ssq[b * T_ + myq], st2);
    }
  }
}

// ---------------------------------------------------------------- launch
extern "C" void kernel_launch(void* const* d_in, const int* in_sizes, int n_in,
                              void* d_out, int out_size, void* d_ws, size_t ws_size,
                              hipStream_t stream)
{
  const float* x        = (const float*)d_in[0];
  const float* c_attn_w = (const float*)d_in[1];
  const float* c_attn_b = (const float*)d_in[2];
  const float* q_w      = (const float*)d_in[3];
  const float* q_b      = (const float*)d_in[4];
  const float* k_w      = (const float*)d_in[5];
  const float* k_b      = (const float*)d_in[6];
  const float* v_w      = (const float*)d_in[7];
  const float* v_b      = (const float*)d_in[8];
  const float* ln_g     = (const float*)d_in[9];
  const float* ln_b     = (const float*)d_in[10];
  const float* out_w    = (const float*)d_in[11];
  const float* out_b    = (const float*)d_in[12];

  char* ws = (char*)d_ws;
  bf16_t* qkvb      = (bf16_t*)(ws + 0);          // [4096][3072]
  bf16_t* xb        = (bf16_t*)(ws + 25165824);   // [4096][1024] dead after qkv
  bf16_t* ob        = (bf16_t*)(ws + 25165824);   // attn output (overlays xb)
  bf16_t* WsT4      = (bf16_t*)(ws + 33554432);   // 4 slabs of 1M bf16
  bf16_t* c_attn_wb = (bf16_t*)(ws + 41943040);   // [1024][3072]
  bf16_t* Wt_eff    = (bf16_t*)(ws + 48234496);   // [3072][1024]
  float*  bias_eff  = (float*)(ws + 54525952);    // [3072]
  bf16_t* vfrag     = (bf16_t*)(ws + 54538240);   // 8 MB fragment-linear V
  float*  ssum      = (float*)(ws + 62926848);    // [4096]
  float*  ssq       = (float*)(ws + 62943232);    // [4096]
  float*  svec      = (float*)(ws + 62959616);    // [1024]
  float*  c2v       = (float*)(ws + 62963712);    // [1024]

  prep_all<<<dim3(11345), 256, 0, stream>>>(
      x, xb, c_attn_w, c_attn_wb,
      q_w, k_w, v_w, out_w, ln_g, WsT4,
      c_attn_b, q_b, k_b, v_b, ln_b, out_b,
      bias_eff, svec, c2v, ssum, ssq);

  // fused weights: 64x64 tiles, 768 blocks (r16-verified)
  gemm_bt_bias<bf16_t, 2, 2><<<dim3(768), 256, 0, stream>>>(
      WsT4, 1024, c_attn_wb, 3072, nullptr, Wt_eff, 1024,
      1024, 16, 256, 1 << 20, 1024, 1 << 20, 1);

  // qkvb = xb @ Wt_eff^T + bias_eff (128x128, 768 blocks — r16-verified best)
  gemm_bt_bias<bf16_t, 4, 4><<<dim3(768), 256, 0, stream>>>(
      xb, 1024, Wt_eff, 1024, bias_eff, qkvb, 3072, 1024, 24, 768, 0, 0, 0, 1);

  transpose_v<<<dim3(1024), 256, 0, stream>>>(qkvb, vfrag);

  // attention: 512 pair-balanced blocks (r18-verified) + defer-max
  attn_kernel<<<dim3(512), 256, 0, stream>>>(qkvb, vfrag, ob, ssum, ssq);

  // final GEMM+LN: 64x64 tiles, 1024 blocks (r17-verified)
  gemm_ln<<<dim3(1024), 256, 0, stream>>>(
      ob, 1024, WsT4 + (size_t)3 * (1 << 20), 1024,
      svec, c2v, ssum, ssq, (float*)d_out, 1024, 1024, 16);
}